// Round 1
// baseline (129.225 us; speedup 1.0000x reference)
//
#include <hip/hip_runtime.h>
#include <hip/hip_bf16.h>
#include <cstdint>

typedef short bf16x8 __attribute__((ext_vector_type(8)));
typedef float f32x4 __attribute__((ext_vector_type(4)));

// Problem constants
// B=2, DIM=128, H=64, W=64, DH=32, HEADS=4, K=7
#define NTOK 8192
#define QSCALE 0.17677669529663687f

// ---------------- K0: convert weights to bf16 ----------------
__global__ __launch_bounds__(256) void k_convw(
    const float* __restrict__ qw, const float* __restrict__ pw,
    const float* __restrict__ w1, const float* __restrict__ w2,
    const float* __restrict__ w3, __hip_bfloat16* __restrict__ dst) {
  int i = blockIdx.x * 256 + threadIdx.x;
  float v;
  if (i < 49152) v = qw[i];
  else if (i < 65536) v = pw[i - 49152];
  else if (i < 81920) v = w1[i - 65536];
  else if (i < 98304) v = w2[i - 81920];
  else if (i < 114688) v = w3[i - 98304];
  else return;
  dst[i] = __float2bfloat16(v);
}

// ---------------- K1: NCHW->NHWC transpose + LN1 ----------------
// grid 128 blocks x 256 thr; each block: one batch, 64 consecutive spatial pos
__global__ __launch_bounds__(256) void k_tln1(
    const float* __restrict__ x, const float* __restrict__ g,
    const float* __restrict__ be, float* __restrict__ r,
    __hip_bfloat16* __restrict__ yb) {
  __shared__ float tile[128][65];
  int b = blockIdx.x >> 6;
  int p0 = (blockIdx.x & 63) * 64;
  int t = threadIdx.x;
  const float* xb = x + b * 128 * 4096;
#pragma unroll
  for (int i = 0; i < 32; ++i) {
    int idx = i * 256 + t;
    int c = idx >> 6, pp = idx & 63;
    tile[c][pp] = xb[c * 4096 + p0 + pp];
  }
  __syncthreads();
  int wid = t >> 6, lane = t & 63;
  float gg0 = g[lane], gg1 = g[lane + 64];
  float bb0 = be[lane], bb1 = be[lane + 64];
#pragma unroll
  for (int it = 0; it < 16; ++it) {
    int pp = wid * 16 + it;
    float v0 = tile[lane][pp], v1 = tile[lane + 64][pp];
    float s = v0 + v1, sq = v0 * v0 + v1 * v1;
#pragma unroll
    for (int off = 32; off; off >>= 1) {
      s += __shfl_xor(s, off);
      sq += __shfl_xor(sq, off);
    }
    float mu = s * (1.f / 128.f);
    float var = sq * (1.f / 128.f) - mu * mu;
    float rs = rsqrtf(var + 1e-5f);
    int n = b * 4096 + p0 + pp;
    r[n * 128 + lane] = v0;
    r[n * 128 + lane + 64] = v1;
    yb[n * 128 + lane] = __float2bfloat16((v0 - mu) * rs * gg0 + bb0);
    yb[n * 128 + lane + 64] = __float2bfloat16((v1 - mu) * rs * gg1 + bb1);
  }
}

// ---------------- GEMM: out[M,N] = A[M,128] @ W[N,128]^T + bias ----------------
// block 256 thr = 4 waves as 2(M) x 2(N); wave tile 16x64; block tile 32x128
// EPI: 0=qkv(stride384,q-scale) 1=plain 2=+res 3=relu 4=w3+res+NCHW-out
template <int EPI>
__global__ __launch_bounds__(256) void k_gemm(
    const __hip_bfloat16* __restrict__ A, const __hip_bfloat16* __restrict__ Wt,
    const float* __restrict__ bias, const float* __restrict__ res,
    float* __restrict__ out) {
  int wid = threadIdx.x >> 6, lane = threadIdx.x & 63;
  int m_base = (blockIdx.x * 2 + (wid >> 1)) * 16;
  int n_base = blockIdx.y * 128 + (wid & 1) * 64;
  int lr = lane & 15, kg = lane >> 4;
  f32x4 acc[4] = {f32x4{0, 0, 0, 0}, f32x4{0, 0, 0, 0}, f32x4{0, 0, 0, 0},
                  f32x4{0, 0, 0, 0}};
#pragma unroll
  for (int ks = 0; ks < 4; ++ks) {
    bf16x8 a = *reinterpret_cast<const bf16x8*>(A + (m_base + lr) * 128 + ks * 32 + kg * 8);
#pragma unroll
    for (int nf = 0; nf < 4; ++nf) {
      bf16x8 bfr = *reinterpret_cast<const bf16x8*>(
          Wt + (n_base + nf * 16 + lr) * 128 + ks * 32 + kg * 8);
      acc[nf] = __builtin_amdgcn_mfma_f32_16x16x32_bf16(a, bfr, acc[nf], 0, 0, 0);
    }
  }
#pragma unroll
  for (int nf = 0; nf < 4; ++nf) {
    int o = n_base + nf * 16 + lr;
    float bv = bias[o];
#pragma unroll
    for (int rr = 0; rr < 4; ++rr) {
      int m = m_base + kg * 4 + rr;
      float v = acc[nf][rr] + bv;
      if constexpr (EPI == 0) {
        if (o < 128) v *= QSCALE;
        out[m * 384 + o] = v;
      } else if constexpr (EPI == 1) {
        out[m * 128 + o] = v;
      } else if constexpr (EPI == 2) {
        out[m * 128 + o] = v + res[m * 128 + o];
      } else if constexpr (EPI == 3) {
        out[m * 128 + o] = fmaxf(v, 0.f);
      } else {
        float vv = v + res[m * 128 + o];
        int bb = m >> 12, hw = m & 4095;
        out[bb * 524288 + o * 4096 + hw] = vv;
      }
    }
  }
}

// ---------------- K3: 7x7 neighborhood attention ----------------
// one wave per token; loop over 4 heads; half-waves process neighbor pairs
__global__ __launch_bounds__(256) void k_attn(
    const float* __restrict__ qkv, const float* __restrict__ rpb,
    __hip_bfloat16* __restrict__ ao) {
  int wid = threadIdx.x >> 6, lane = threadIdx.x & 63;
  int n = blockIdx.x * 4 + wid;
  int b = n >> 12, p = n & 4095, h = p >> 6, w = p & 63;
  int hs = min(max(h - 3, 0), 57), ws0 = min(max(w - 3, 0), 57);
  int hi = lane >> 5;
  int d = lane & 31;
  const float* base = qkv + (size_t)n * 384;
  float sarr[25];
#pragma unroll 1
  for (int hd = 0; hd < 4; ++hd) {
    float qv = base[hd * 32 + d];  // q pre-scaled in GEMM epilogue
    // ---- QK^T: 2 neighbors per iter (one per half-wave) ----
#pragma unroll
    for (int jj = 0; jj < 25; ++jj) {
      int j = jj * 2 + hi;
      float sc = 0.f;
      int i7 = j / 7, jc = j - i7 * 7;
      if (j < 49) {
        int tn = b * 4096 + (hs + i7) * 64 + (ws0 + jc);
        sc = qv * qkv[(size_t)tn * 384 + 128 + hd * 32 + d];
      }
#pragma unroll
      for (int off = 16; off; off >>= 1) sc += __shfl_xor(sc, off, 32);
      if (j < 49) {
        int bih = hs + i7 - h + 6, biw = ws0 + jc - w + 6;
        sc += rpb[hd * 169 + bih * 13 + biw];
      } else {
        sc = -1e30f;
      }
      sarr[jj] = sc;
    }
    // ---- softmax over 49 (split even/odd across half-waves) ----
    float mx = -1e30f;
#pragma unroll
    for (int jj = 0; jj < 25; ++jj) mx = fmaxf(mx, sarr[jj]);
    mx = fmaxf(mx, __shfl_xor(mx, 32));
    float sum = 0.f;
#pragma unroll
    for (int jj = 0; jj < 25; ++jj) {
      sarr[jj] = __expf(sarr[jj] - mx);
      sum += sarr[jj];
    }
    sum += __shfl_xor(sum, 32);
    float inv = 1.f / sum;
    // ---- PV ----
    float acc = 0.f;
#pragma unroll
    for (int jj = 0; jj < 25; ++jj) {
      int j = jj * 2 + hi;
      if (j < 49) {
        int i7 = j / 7, jc = j - i7 * 7;
        int tn = b * 4096 + (hs + i7) * 64 + (ws0 + jc);
        acc += sarr[jj] * qkv[(size_t)tn * 384 + 256 + hd * 32 + d];
      }
    }
    acc += __shfl_xor(acc, 32);
    acc *= inv;
    if (hi == 0) ao[n * 128 + hd * 32 + d] = __float2bfloat16(acc);
  }
}

// ---------------- LN (f32 in -> bf16 out) ----------------
__global__ __launch_bounds__(256) void k_ln(
    const float* __restrict__ in, const float* __restrict__ g,
    const float* __restrict__ be, __hip_bfloat16* __restrict__ out) {
  int wid = threadIdx.x >> 6, lane = threadIdx.x & 63;
  int n = blockIdx.x * 4 + wid;
  float2 v = *reinterpret_cast<const float2*>(in + n * 128 + lane * 2);
  float s = v.x + v.y, sq = v.x * v.x + v.y * v.y;
#pragma unroll
  for (int off = 32; off; off >>= 1) {
    s += __shfl_xor(s, off);
    sq += __shfl_xor(sq, off);
  }
  float mu = s * (1.f / 128.f);
  float var = sq * (1.f / 128.f) - mu * mu;
  float rs = rsqrtf(var + 1e-5f);
  float y0 = (v.x - mu) * rs * g[lane * 2] + be[lane * 2];
  float y1 = (v.y - mu) * rs * g[lane * 2 + 1] + be[lane * 2 + 1];
  out[n * 128 + lane * 2] = __float2bfloat16(y0);
  out[n * 128 + lane * 2 + 1] = __float2bfloat16(y1);
}

// ---------------- launch ----------------
extern "C" void kernel_launch(void* const* d_in, const int* in_sizes, int n_in,
                              void* d_out, int out_size, void* d_ws,
                              size_t ws_size, hipStream_t stream) {
  const float* x = (const float*)d_in[0];
  const float* g1 = (const float*)d_in[1];
  const float* be1 = (const float*)d_in[2];
  const float* g2 = (const float*)d_in[3];
  const float* be2 = (const float*)d_in[4];
  const float* g3 = (const float*)d_in[5];
  const float* be3 = (const float*)d_in[6];
  const float* g4 = (const float*)d_in[7];
  const float* be4 = (const float*)d_in[8];
  const float* qkv_w = (const float*)d_in[9];
  const float* qkv_b = (const float*)d_in[10];
  const float* rpb = (const float*)d_in[11];
  const float* proj_w = (const float*)d_in[12];
  const float* proj_b = (const float*)d_in[13];
  const float* w1 = (const float*)d_in[14];
  const float* bl1 = (const float*)d_in[15];
  const float* w2 = (const float*)d_in[16];
  const float* bl2 = (const float*)d_in[17];
  const float* w3 = (const float*)d_in[18];
  const float* bl3 = (const float*)d_in[19];

  char* ws = (char*)d_ws;
  __hip_bfloat16* wb = (__hip_bfloat16*)ws;          // 114688 bf16 elems
  __hip_bfloat16* wb_qkv = wb;                       // [384][128]
  __hip_bfloat16* wb_proj = wb + 49152;              // [128][128]
  __hip_bfloat16* wb_w1 = wb + 65536;
  __hip_bfloat16* wb_w2 = wb + 81920;
  __hip_bfloat16* wb_w3 = wb + 98304;
  float* r = (float*)(ws + 262144);                  // [8192][128] f32 residual
  __hip_bfloat16* yb = (__hip_bfloat16*)(ws + 4456448);   // [8192][128] bf16
  float* qkvb = (float*)(ws + 6553600);              // [8192][384] f32
  __hip_bfloat16* ao = (__hip_bfloat16*)(ws + 19136512);  // [8192][128] bf16
  float* pbuf = (float*)(ws + 21233664);             // [8192][128] f32
  float* x2 = (float*)(ws + 25427968);               // [8192][128] f32

  k_convw<<<448, 256, 0, stream>>>(qkv_w, proj_w, w1, w2, w3, wb);
  k_tln1<<<128, 256, 0, stream>>>(x, g1, be1, r, yb);
  k_gemm<0><<<dim3(256, 3), 256, 0, stream>>>(yb, wb_qkv, qkv_b, nullptr, qkvb);
  k_attn<<<2048, 256, 0, stream>>>(qkvb, rpb, ao);
  k_gemm<1><<<dim3(256, 1), 256, 0, stream>>>(ao, wb_proj, proj_b, nullptr, pbuf);
  k_ln<<<2048, 256, 0, stream>>>(pbuf, g2, be2, yb);
  k_gemm<2><<<dim3(256, 1), 256, 0, stream>>>(yb, wb_w1, bl1, r, x2);
  k_ln<<<2048, 256, 0, stream>>>(x2, g3, be3, yb);
  k_gemm<3><<<dim3(256, 1), 256, 0, stream>>>(yb, wb_w2, bl2, nullptr, pbuf);
  k_ln<<<2048, 256, 0, stream>>>(pbuf, g4, be4, yb);
  k_gemm<4><<<dim3(256, 1), 256, 0, stream>>>(yb, wb_w3, bl3, x2, (float*)d_out);
}

// Round 3
// 94.490 us; speedup vs baseline: 1.3676x; 1.3676x over previous
//
#include <hip/hip_runtime.h>
#include <hip/hip_bf16.h>
#include <cstdint>

typedef short bf16x8 __attribute__((ext_vector_type(8)));
typedef float f32x4 __attribute__((ext_vector_type(4)));

// Problem constants: B=2, DIM=128, H=64, W=64, DH=32, HEADS=4, K=7
#define NTOK 8192
#define QSCALE 0.17677669529663687f

__device__ inline float b2f(short s) {
  return __uint_as_float(((unsigned)(unsigned short)s) << 16);
}

// ---------------- K0: convert weights to bf16 ----------------
__global__ __launch_bounds__(256) void k_convw(
    const float* __restrict__ qw, const float* __restrict__ pw,
    const float* __restrict__ w1, const float* __restrict__ w2,
    const float* __restrict__ w3, __hip_bfloat16* __restrict__ dst) {
  int i = blockIdx.x * 256 + threadIdx.x;
  float v;
  if (i < 49152) v = qw[i];
  else if (i < 65536) v = pw[i - 49152];
  else if (i < 81920) v = w1[i - 65536];
  else if (i < 98304) v = w2[i - 81920];
  else if (i < 114688) v = w3[i - 98304];
  else return;
  dst[i] = __float2bfloat16(v);
}

// ---------------- K1: NCHW->NHWC transpose + LN1 ----------------
__global__ __launch_bounds__(256) void k_tln1(
    const float* __restrict__ x, const float* __restrict__ g,
    const float* __restrict__ be, float* __restrict__ r,
    __hip_bfloat16* __restrict__ yb) {
  __shared__ float tile[128][65];
  int b = blockIdx.x >> 6;
  int p0 = (blockIdx.x & 63) * 64;
  int t = threadIdx.x;
  const float* xb = x + b * 128 * 4096;
#pragma unroll
  for (int i = 0; i < 32; ++i) {
    int idx = i * 256 + t;
    int c = idx >> 6, pp = idx & 63;
    tile[c][pp] = xb[c * 4096 + p0 + pp];
  }
  __syncthreads();
  int wid = t >> 6, lane = t & 63;
  float gg0 = g[lane], gg1 = g[lane + 64];
  float bb0 = be[lane], bb1 = be[lane + 64];
#pragma unroll
  for (int it = 0; it < 16; ++it) {
    int pp = wid * 16 + it;
    float v0 = tile[lane][pp], v1 = tile[lane + 64][pp];
    float s = v0 + v1, sq = v0 * v0 + v1 * v1;
#pragma unroll
    for (int off = 32; off; off >>= 1) {
      s += __shfl_xor(s, off);
      sq += __shfl_xor(sq, off);
    }
    float mu = s * (1.f / 128.f);
    float var = sq * (1.f / 128.f) - mu * mu;
    float rs = rsqrtf(var + 1e-5f);
    int n = b * 4096 + p0 + pp;
    r[n * 128 + lane] = v0;
    r[n * 128 + lane + 64] = v1;
    yb[n * 128 + lane] = __float2bfloat16((v0 - mu) * rs * gg0 + bb0);
    yb[n * 128 + lane + 64] = __float2bfloat16((v1 - mu) * rs * gg1 + bb1);
  }
}

// ---------------- GEMM: out[M,N] = A[M,128] @ W[N,128]^T + bias ----------------
// EPI: 0=qkv(stride384,q-scale,bf16 out) 1=plain 2=+res 3=relu 4=w3+res+NCHW-out
template <int EPI>
__global__ __launch_bounds__(256) void k_gemm(
    const __hip_bfloat16* __restrict__ A, const __hip_bfloat16* __restrict__ Wt,
    const float* __restrict__ bias, const float* __restrict__ res,
    void* __restrict__ outv) {
  int wid = threadIdx.x >> 6, lane = threadIdx.x & 63;
  int m_base = (blockIdx.x * 2 + (wid >> 1)) * 16;
  int n_base = blockIdx.y * 128 + (wid & 1) * 64;
  int lr = lane & 15, kg = lane >> 4;
  f32x4 acc[4] = {f32x4{0, 0, 0, 0}, f32x4{0, 0, 0, 0}, f32x4{0, 0, 0, 0},
                  f32x4{0, 0, 0, 0}};
#pragma unroll
  for (int ks = 0; ks < 4; ++ks) {
    bf16x8 a = *reinterpret_cast<const bf16x8*>(A + (m_base + lr) * 128 + ks * 32 + kg * 8);
#pragma unroll
    for (int nf = 0; nf < 4; ++nf) {
      bf16x8 bfr = *reinterpret_cast<const bf16x8*>(
          Wt + (n_base + nf * 16 + lr) * 128 + ks * 32 + kg * 8);
      acc[nf] = __builtin_amdgcn_mfma_f32_16x16x32_bf16(a, bfr, acc[nf], 0, 0, 0);
    }
  }
#pragma unroll
  for (int nf = 0; nf < 4; ++nf) {
    int o = n_base + nf * 16 + lr;
    float bv = bias[o];
#pragma unroll
    for (int rr = 0; rr < 4; ++rr) {
      int m = m_base + kg * 4 + rr;
      float v = acc[nf][rr] + bv;
      if constexpr (EPI == 0) {
        if (o < 128) v *= QSCALE;
        ((__hip_bfloat16*)outv)[m * 384 + o] = __float2bfloat16(v);
      } else if constexpr (EPI == 1) {
        ((float*)outv)[m * 128 + o] = v;
      } else if constexpr (EPI == 2) {
        ((float*)outv)[m * 128 + o] = v + res[m * 128 + o];
      } else if constexpr (EPI == 3) {
        ((float*)outv)[m * 128 + o] = fmaxf(v, 0.f);
      } else {
        float vv = v + res[m * 128 + o];
        int bb = m >> 12, hw = m & 4095;
        ((float*)outv)[bb * 524288 + o * 4096 + hw] = vv;
      }
    }
  }
}

// ---------------- Attention phase A: scores + softmax ----------------
// block = one token, wave = one head, lane = neighbor (j<49)
__global__ __launch_bounds__(256) void k_attn_score(
    const __hip_bfloat16* __restrict__ qkv, const float* __restrict__ rpb,
    float* __restrict__ P) {
  int n = blockIdx.x;
  int h = threadIdx.x >> 6;
  int j = threadIdx.x & 63;
  int b = n >> 12, p = n & 4095, hq = p >> 6, wq = p & 63;
  int hs = min(max(hq - 3, 0), 57), ws0 = min(max(wq - 3, 0), 57);
  bool act = j < 49;
  int i7 = j / 7, jc = j - i7 * 7;
  // q broadcast (same 64B for all lanes of the wave)
  const __hip_bfloat16* qp = qkv + (size_t)n * 384 + h * 32;
  float q[32];
#pragma unroll
  for (int g = 0; g < 4; ++g) {
    bf16x8 v = *reinterpret_cast<const bf16x8*>(qp + g * 8);
#pragma unroll
    for (int e = 0; e < 8; ++e) q[g * 8 + e] = b2f(v[e]);
  }
  float sc = -1e30f;
  if (act) {
    int tn = b * 4096 + (hs + i7) * 64 + (ws0 + jc);
    const __hip_bfloat16* kp = qkv + (size_t)tn * 384 + 128 + h * 32;
    float s = 0.f;
#pragma unroll
    for (int g = 0; g < 4; ++g) {
      bf16x8 kv = *reinterpret_cast<const bf16x8*>(kp + g * 8);
#pragma unroll
      for (int e = 0; e < 8; ++e) s += q[g * 8 + e] * b2f(kv[e]);
    }
    int bih = hs + i7 - hq + 6, biw = ws0 + jc - wq + 6;
    sc = s + rpb[h * 169 + bih * 13 + biw];
  }
  float mx = sc;
#pragma unroll
  for (int off = 32; off; off >>= 1) mx = fmaxf(mx, __shfl_xor(mx, off));
  float pj = act ? __expf(sc - mx) : 0.f;
  float sum = pj;
#pragma unroll
  for (int off = 32; off; off >>= 1) sum += __shfl_xor(sum, off);
  P[((size_t)n * 4 + h) * 64 + j] = pj * (1.f / sum);
}

// ---------------- Attention phase B: PV ----------------
// thread = (token, head, d-pair); one wave = one token (coalesced V reads)
__global__ __launch_bounds__(256) void k_attn_pv(
    const __hip_bfloat16* __restrict__ qkv, const float* __restrict__ P,
    __hip_bfloat16* __restrict__ ao) {
  int id = blockIdx.x * 256 + threadIdx.x;
  int n = id >> 6;
  int h = (id >> 4) & 3, dp = id & 15;
  int b = n >> 12, p = n & 4095, hq = p >> 6, wq = p & 63;
  int hs = min(max(hq - 3, 0), 57), ws0 = min(max(wq - 3, 0), 57);
  const __hip_bfloat16* vbase =
      qkv + ((size_t)(b * 4096 + hs * 64 + ws0)) * 384 + 256 + h * 32 + dp * 2;
  const float* pp = P + ((size_t)n * 4 + h) * 64;
  float a0 = 0.f, a1 = 0.f;
#pragma unroll
  for (int i7 = 0; i7 < 7; ++i7) {
#pragma unroll
    for (int jc = 0; jc < 7; ++jc) {
      float pj = pp[i7 * 7 + jc];
      unsigned kv = *reinterpret_cast<const unsigned*>(vbase + (i7 * 64 + jc) * 384);
      a0 += pj * __uint_as_float(kv << 16);
      a1 += pj * __uint_as_float(kv & 0xffff0000u);
    }
  }
  __hip_bfloat162 o;
  o.x = __float2bfloat16(a0);
  o.y = __float2bfloat16(a1);
  *reinterpret_cast<__hip_bfloat162*>(ao + (size_t)n * 128 + h * 32 + dp * 2) = o;
}

// ---------------- LN (f32 in -> bf16 out) ----------------
__global__ __launch_bounds__(256) void k_ln(
    const float* __restrict__ in, const float* __restrict__ g,
    const float* __restrict__ be, __hip_bfloat16* __restrict__ out) {
  int wid = threadIdx.x >> 6, lane = threadIdx.x & 63;
  int n = blockIdx.x * 4 + wid;
  float2 v = *reinterpret_cast<const float2*>(in + n * 128 + lane * 2);
  float s = v.x + v.y, sq = v.x * v.x + v.y * v.y;
#pragma unroll
  for (int off = 32; off; off >>= 1) {
    s += __shfl_xor(s, off);
    sq += __shfl_xor(sq, off);
  }
  float mu = s * (1.f / 128.f);
  float var = sq * (1.f / 128.f) - mu * mu;
  float rs = rsqrtf(var + 1e-5f);
  float y0 = (v.x - mu) * rs * g[lane * 2] + be[lane * 2];
  float y1 = (v.y - mu) * rs * g[lane * 2 + 1] + be[lane * 2 + 1];
  out[n * 128 + lane * 2] = __float2bfloat16(y0);
  out[n * 128 + lane * 2 + 1] = __float2bfloat16(y1);
}

// ---------------- launch ----------------
extern "C" void kernel_launch(void* const* d_in, const int* in_sizes, int n_in,
                              void* d_out, int out_size, void* d_ws,
                              size_t ws_size, hipStream_t stream) {
  const float* x = (const float*)d_in[0];
  const float* g1 = (const float*)d_in[1];
  const float* be1 = (const float*)d_in[2];
  const float* g2 = (const float*)d_in[3];
  const float* be2 = (const float*)d_in[4];
  const float* g3 = (const float*)d_in[5];
  const float* be3 = (const float*)d_in[6];
  const float* g4 = (const float*)d_in[7];
  const float* be4 = (const float*)d_in[8];
  const float* qkv_w = (const float*)d_in[9];
  const float* qkv_b = (const float*)d_in[10];
  const float* rpb = (const float*)d_in[11];
  const float* proj_w = (const float*)d_in[12];
  const float* proj_b = (const float*)d_in[13];
  const float* w1 = (const float*)d_in[14];
  const float* bl1 = (const float*)d_in[15];
  const float* w2 = (const float*)d_in[16];
  const float* bl2 = (const float*)d_in[17];
  const float* w3 = (const float*)d_in[18];
  const float* bl3 = (const float*)d_in[19];

  char* ws = (char*)d_ws;
  __hip_bfloat16* wb = (__hip_bfloat16*)ws;             // weights bf16
  __hip_bfloat16* wb_qkv = wb;                          // [384][128]
  __hip_bfloat16* wb_proj = wb + 49152;
  __hip_bfloat16* wb_w1 = wb + 65536;
  __hip_bfloat16* wb_w2 = wb + 81920;
  __hip_bfloat16* wb_w3 = wb + 98304;
  float* r = (float*)(ws + 262144);                     // [8192][128] f32
  __hip_bfloat16* yb = (__hip_bfloat16*)(ws + 4456448); // [8192][128] bf16
  __hip_bfloat16* qkvb = (__hip_bfloat16*)(ws + 6553600); // [8192][384] bf16
  __hip_bfloat16* ao = (__hip_bfloat16*)(ws + 12845056);  // [8192][128] bf16
  float* P = (float*)(ws + 14942208);                   // [8192][4][64] f32 (8MB)
  float* pbuf = (float*)(ws + 14942208);                // aliases P (after B)
  float* x2 = (float*)(ws + 19136512);                  // aliases P upper half

  k_convw<<<448, 256, 0, stream>>>(qkv_w, proj_w, w1, w2, w3, wb);
  k_tln1<<<128, 256, 0, stream>>>(x, g1, be1, r, yb);
  k_gemm<0><<<dim3(256, 3), 256, 0, stream>>>(yb, wb_qkv, qkv_b, nullptr, qkvb);
  k_attn_score<<<8192, 256, 0, stream>>>(qkvb, rpb, P);
  k_attn_pv<<<2048, 256, 0, stream>>>(qkvb, P, ao);
  k_gemm<1><<<dim3(256, 1), 256, 0, stream>>>(ao, wb_proj, proj_b, nullptr, pbuf);
  k_ln<<<2048, 256, 0, stream>>>(pbuf, g2, be2, yb);
  k_gemm<2><<<dim3(256, 1), 256, 0, stream>>>(yb, wb_w1, bl1, r, x2);
  k_ln<<<2048, 256, 0, stream>>>(x2, g3, be3, yb);
  k_gemm<3><<<dim3(256, 1), 256, 0, stream>>>(yb, wb_w2, bl2, nullptr, pbuf);
  k_ln<<<2048, 256, 0, stream>>>(pbuf, g4, be4, yb);
  k_gemm<4><<<dim3(256, 1), 256, 0, stream>>>(yb, wb_w3, bl3, x2, (float*)d_out);
}

// Round 4
// 81.068 us; speedup vs baseline: 1.5940x; 1.1656x over previous
//
#include <hip/hip_runtime.h>
#include <hip/hip_bf16.h>
#include <cstdint>

typedef short bf16x8 __attribute__((ext_vector_type(8)));
typedef float f32x4 __attribute__((ext_vector_type(4)));

// Problem constants: B=2, DIM=128, H=64, W=64, DH=32, HEADS=4, K=7
#define NTOK 8192
#define QSCALE 0.17677669529663687f

__device__ inline float b2f(short s) {
  return __uint_as_float(((unsigned)(unsigned short)s) << 16);
}

// ---------------- K0: convert weights to bf16 ----------------
__global__ __launch_bounds__(256) void k_convw(
    const float* __restrict__ qw, const float* __restrict__ pw,
    const float* __restrict__ w1, const float* __restrict__ w2,
    const float* __restrict__ w3, __hip_bfloat16* __restrict__ dst) {
  int i = blockIdx.x * 256 + threadIdx.x;
  float v;
  if (i < 49152) v = qw[i];
  else if (i < 65536) v = pw[i - 49152];
  else if (i < 81920) v = w1[i - 65536];
  else if (i < 98304) v = w2[i - 81920];
  else if (i < 114688) v = w3[i - 98304];
  else return;
  dst[i] = __float2bfloat16(v);
}

// ---------------- K1: NCHW->NHWC transpose + LN1 ----------------
__global__ __launch_bounds__(256) void k_tln1(
    const float* __restrict__ x, const float* __restrict__ g,
    const float* __restrict__ be, float* __restrict__ r,
    __hip_bfloat16* __restrict__ yb) {
  __shared__ float tile[128][65];
  int b = blockIdx.x >> 6;
  int p0 = (blockIdx.x & 63) * 64;
  int t = threadIdx.x;
  const float* xb = x + b * 128 * 4096;
#pragma unroll
  for (int i = 0; i < 32; ++i) {
    int idx = i * 256 + t;
    int c = idx >> 6, pp = idx & 63;
    tile[c][pp] = xb[c * 4096 + p0 + pp];
  }
  __syncthreads();
  int wid = t >> 6, lane = t & 63;
  float gg0 = g[lane], gg1 = g[lane + 64];
  float bb0 = be[lane], bb1 = be[lane + 64];
#pragma unroll
  for (int it = 0; it < 16; ++it) {
    int pp = wid * 16 + it;
    float v0 = tile[lane][pp], v1 = tile[lane + 64][pp];
    float s = v0 + v1, sq = v0 * v0 + v1 * v1;
#pragma unroll
    for (int off = 32; off; off >>= 1) {
      s += __shfl_xor(s, off);
      sq += __shfl_xor(sq, off);
    }
    float mu = s * (1.f / 128.f);
    float var = sq * (1.f / 128.f) - mu * mu;
    float rs = rsqrtf(var + 1e-5f);
    int n = b * 4096 + p0 + pp;
    r[n * 128 + lane] = v0;
    r[n * 128 + lane + 64] = v1;
    yb[n * 128 + lane] = __float2bfloat16((v0 - mu) * rs * gg0 + bb0);
    yb[n * 128 + lane + 64] = __float2bfloat16((v1 - mu) * rs * gg1 + bb1);
  }
}

// ---------------- GEMM (no LN): EPI 0=qkv(bf16,q-scale) 4=w3+res+NCHW f32 out ----------------
template <int EPI>
__global__ __launch_bounds__(256) void k_gemm(
    const __hip_bfloat16* __restrict__ A, const __hip_bfloat16* __restrict__ Wt,
    const float* __restrict__ bias, const float* __restrict__ res,
    void* __restrict__ outv) {
  int wid = threadIdx.x >> 6, lane = threadIdx.x & 63;
  int m_base = (blockIdx.x * 2 + (wid >> 1)) * 16;
  int n_base = blockIdx.y * 128 + (wid & 1) * 64;
  int lr = lane & 15, kg = lane >> 4;
  f32x4 acc[4] = {f32x4{0, 0, 0, 0}, f32x4{0, 0, 0, 0}, f32x4{0, 0, 0, 0},
                  f32x4{0, 0, 0, 0}};
#pragma unroll
  for (int ks = 0; ks < 4; ++ks) {
    bf16x8 a = *reinterpret_cast<const bf16x8*>(A + (m_base + lr) * 128 + ks * 32 + kg * 8);
#pragma unroll
    for (int nf = 0; nf < 4; ++nf) {
      bf16x8 bfr = *reinterpret_cast<const bf16x8*>(
          Wt + (n_base + nf * 16 + lr) * 128 + ks * 32 + kg * 8);
      acc[nf] = __builtin_amdgcn_mfma_f32_16x16x32_bf16(a, bfr, acc[nf], 0, 0, 0);
    }
  }
#pragma unroll
  for (int nf = 0; nf < 4; ++nf) {
    int o = n_base + nf * 16 + lr;
    float bv = bias[o];
#pragma unroll
    for (int rr = 0; rr < 4; ++rr) {
      int m = m_base + kg * 4 + rr;
      float v = acc[nf][rr] + bv;
      if constexpr (EPI == 0) {
        if (o < 128) v *= QSCALE;
        ((__hip_bfloat16*)outv)[m * 384 + o] = __float2bfloat16(v);
      } else {
        float vv = v + res[m * 128 + o];
        int bb = m >> 12, hw = m & 4095;
        ((float*)outv)[bb * 524288 + o * 4096 + hw] = vv;
      }
    }
  }
}

// ---------------- GEMM + fused LayerNorm over the 128-col row ----------------
// EPI: 1 = plain (proj -> LN2)   2 = +res, also store f32 pre-LN (w1 -> x2, LN3)
// EPI: 3 = relu (w2 -> LN4)
template <int EPI>
__global__ __launch_bounds__(256) void k_gemmln(
    const __hip_bfloat16* __restrict__ A, const __hip_bfloat16* __restrict__ Wt,
    const float* __restrict__ bias, const float* __restrict__ res,
    float* __restrict__ outf, __hip_bfloat16* __restrict__ outb,
    const float* __restrict__ g, const float* __restrict__ be) {
  __shared__ float2 red[2][2][16];
  int wid = threadIdx.x >> 6, lane = threadIdx.x & 63;
  int mw = wid >> 1, nw = wid & 1;
  int m_base = (blockIdx.x * 2 + mw) * 16;
  int n_base = nw * 64;
  int lr = lane & 15, kg = lane >> 4;
  f32x4 acc[4] = {f32x4{0, 0, 0, 0}, f32x4{0, 0, 0, 0}, f32x4{0, 0, 0, 0},
                  f32x4{0, 0, 0, 0}};
#pragma unroll
  for (int ks = 0; ks < 4; ++ks) {
    bf16x8 a = *reinterpret_cast<const bf16x8*>(A + (m_base + lr) * 128 + ks * 32 + kg * 8);
#pragma unroll
    for (int nf = 0; nf < 4; ++nf) {
      bf16x8 bfr = *reinterpret_cast<const bf16x8*>(
          Wt + (n_base + nf * 16 + lr) * 128 + ks * 32 + kg * 8);
      acc[nf] = __builtin_amdgcn_mfma_f32_16x16x32_bf16(a, bfr, acc[nf], 0, 0, 0);
    }
  }
  // finalize v, accumulate per-row partial sums over this wave's 64 cols
  float ps[4] = {0.f, 0.f, 0.f, 0.f}, pq[4] = {0.f, 0.f, 0.f, 0.f};
#pragma unroll
  for (int nf = 0; nf < 4; ++nf) {
    int o = n_base + nf * 16 + lr;
    float bv = bias[o];
#pragma unroll
    for (int rr = 0; rr < 4; ++rr) {
      float v = acc[nf][rr] + bv;
      if constexpr (EPI == 2) v += res[(m_base + kg * 4 + rr) * 128 + o];
      if constexpr (EPI == 3) v = fmaxf(v, 0.f);
      acc[nf][rr] = v;
      ps[rr] += v;
      pq[rr] += v * v;
    }
  }
  // reduce across the 16 lanes sharing kg (lr bits 0..3)
#pragma unroll
  for (int rr = 0; rr < 4; ++rr) {
#pragma unroll
    for (int off = 1; off < 16; off <<= 1) {
      ps[rr] += __shfl_xor(ps[rr], off);
      pq[rr] += __shfl_xor(pq[rr], off);
    }
  }
  if (lr == 0) {
#pragma unroll
    for (int rr = 0; rr < 4; ++rr)
      red[mw][nw][kg * 4 + rr] = make_float2(ps[rr], pq[rr]);
  }
  __syncthreads();
  float mu[4], rsv[4];
#pragma unroll
  for (int rr = 0; rr < 4; ++rr) {
    int r16 = kg * 4 + rr;
    float2 a0 = red[mw][0][r16], a1 = red[mw][1][r16];
    float s = a0.x + a1.x, q = a0.y + a1.y;
    mu[rr] = s * (1.f / 128.f);
    float var = q * (1.f / 128.f) - mu[rr] * mu[rr];
    rsv[rr] = rsqrtf(var + 1e-5f);
  }
#pragma unroll
  for (int nf = 0; nf < 4; ++nf) {
    int o = n_base + nf * 16 + lr;
    float gv = g[o], bev = be[o];
#pragma unroll
    for (int rr = 0; rr < 4; ++rr) {
      int m = m_base + kg * 4 + rr;
      if constexpr (EPI == 2) outf[m * 128 + o] = acc[nf][rr];
      float y = (acc[nf][rr] - mu[rr]) * rsv[rr] * gv + bev;
      outb[m * 128 + o] = __float2bfloat16(y);
    }
  }
}

// ---------------- Fused 7x7 neighborhood attention ----------------
// block = one token, wave = one head; phase A lane=neighbor; P via LDS; phase B half-waves over d
__global__ __launch_bounds__(256) void k_attn2(
    const __hip_bfloat16* __restrict__ qkv, const float* __restrict__ rpb,
    __hip_bfloat16* __restrict__ ao) {
  __shared__ float P[4][64];
  int n = blockIdx.x;
  int h = threadIdx.x >> 6, lane = threadIdx.x & 63;
  int b = n >> 12, p = n & 4095, hq = p >> 6, wq = p & 63;
  int hs = min(max(hq - 3, 0), 57), ws0 = min(max(wq - 3, 0), 57);
  // ---- phase A: scores + softmax, lane = neighbor ----
  int j = lane;
  bool act = j < 49;
  int i7 = j / 7, jc = j - i7 * 7;
  const __hip_bfloat16* qp = qkv + (size_t)n * 384 + h * 32;
  float q[32];
#pragma unroll
  for (int gq = 0; gq < 4; ++gq) {
    bf16x8 v = *reinterpret_cast<const bf16x8*>(qp + gq * 8);
#pragma unroll
    for (int e = 0; e < 8; ++e) q[gq * 8 + e] = b2f(v[e]);
  }
  float sc = -1e30f;
  if (act) {
    int tn = b * 4096 + (hs + i7) * 64 + (ws0 + jc);
    const __hip_bfloat16* kp = qkv + (size_t)tn * 384 + 128 + h * 32;
    float s = 0.f;
#pragma unroll
    for (int gq = 0; gq < 4; ++gq) {
      bf16x8 kv = *reinterpret_cast<const bf16x8*>(kp + gq * 8);
#pragma unroll
      for (int e = 0; e < 8; ++e) s += q[gq * 8 + e] * b2f(kv[e]);
    }
    int bih = hs + i7 - hq + 6, biw = ws0 + jc - wq + 6;
    sc = s + rpb[h * 169 + bih * 13 + biw];
  }
  float mx = sc;
#pragma unroll
  for (int off = 32; off; off >>= 1) mx = fmaxf(mx, __shfl_xor(mx, off));
  float pj = act ? __expf(sc - mx) : 0.f;
  float sum = pj;
#pragma unroll
  for (int off = 32; off; off >>= 1) sum += __shfl_xor(sum, off);
  P[h][j] = pj * (1.f / sum);
  __syncthreads();
  // ---- phase B: PV, half-waves cover d, two neighbors per iter ----
  int hi = lane >> 5, d = lane & 31;
  float acc2 = 0.f;
#pragma unroll
  for (int jj = 0; jj < 25; ++jj) {
    int j2 = jj * 2 + hi;  // 0..49
    float pv = P[h][j2];
    int ii = j2 / 7, cc = j2 - ii * 7;
    ii = min(ii, 6);
    int tn = b * 4096 + (hs + ii) * 64 + (ws0 + min(cc, 6));
    float v = b2f(*reinterpret_cast<const short*>(
        qkv + (size_t)tn * 384 + 256 + h * 32 + d));
    acc2 += pv * v;
  }
  acc2 += __shfl_xor(acc2, 32);
  if (hi == 0) ao[(size_t)n * 128 + h * 32 + d] = __float2bfloat16(acc2);
}

// ---------------- launch ----------------
extern "C" void kernel_launch(void* const* d_in, const int* in_sizes, int n_in,
                              void* d_out, int out_size, void* d_ws,
                              size_t ws_size, hipStream_t stream) {
  const float* x = (const float*)d_in[0];
  const float* g1 = (const float*)d_in[1];
  const float* be1 = (const float*)d_in[2];
  const float* g2 = (const float*)d_in[3];
  const float* be2 = (const float*)d_in[4];
  const float* g3 = (const float*)d_in[5];
  const float* be3 = (const float*)d_in[6];
  const float* g4 = (const float*)d_in[7];
  const float* be4 = (const float*)d_in[8];
  const float* qkv_w = (const float*)d_in[9];
  const float* qkv_b = (const float*)d_in[10];
  const float* rpb = (const float*)d_in[11];
  const float* proj_w = (const float*)d_in[12];
  const float* proj_b = (const float*)d_in[13];
  const float* w1 = (const float*)d_in[14];
  const float* bl1 = (const float*)d_in[15];
  const float* w2 = (const float*)d_in[16];
  const float* bl2 = (const float*)d_in[17];
  const float* w3 = (const float*)d_in[18];
  const float* bl3 = (const float*)d_in[19];

  char* ws = (char*)d_ws;
  __hip_bfloat16* wb = (__hip_bfloat16*)ws;               // weights bf16
  __hip_bfloat16* wb_qkv = wb;                            // [384][128]
  __hip_bfloat16* wb_proj = wb + 49152;
  __hip_bfloat16* wb_w1 = wb + 65536;
  __hip_bfloat16* wb_w2 = wb + 81920;
  __hip_bfloat16* wb_w3 = wb + 98304;
  float* r = (float*)(ws + 262144);                       // [8192][128] f32
  __hip_bfloat16* yb = (__hip_bfloat16*)(ws + 4456448);   // [8192][128] bf16
  __hip_bfloat16* qkvb = (__hip_bfloat16*)(ws + 6553600); // [8192][384] bf16
  __hip_bfloat16* ao = (__hip_bfloat16*)(ws + 12845056);  // [8192][128] bf16
  float* x2 = (float*)(ws + 14942208);                    // [8192][128] f32

  k_convw<<<448, 256, 0, stream>>>(qkv_w, proj_w, w1, w2, w3, wb);
  k_tln1<<<128, 256, 0, stream>>>(x, g1, be1, r, yb);
  k_gemm<0><<<dim3(256, 3), 256, 0, stream>>>(yb, wb_qkv, qkv_b, nullptr, qkvb);
  k_attn2<<<8192, 256, 0, stream>>>(qkvb, rpb, ao);
  k_gemmln<1><<<256, 256, 0, stream>>>(ao, wb_proj, proj_b, nullptr, nullptr, yb, g2, be2);
  k_gemmln<2><<<256, 256, 0, stream>>>(yb, wb_w1, bl1, r, x2, yb, g3, be3);
  k_gemmln<3><<<256, 256, 0, stream>>>(yb, wb_w2, bl2, nullptr, nullptr, yb, g4, be4);
  k_gemm<4><<<dim3(256, 1), 256, 0, stream>>>(yb, wb_w3, bl3, x2, (float*)d_out);
}

// Round 5
// 63.501 us; speedup vs baseline: 2.0350x; 1.2766x over previous
//
#include <hip/hip_runtime.h>
#include <hip/hip_bf16.h>
#include <cstdint>

typedef short bf16x8 __attribute__((ext_vector_type(8)));
typedef float f32x4 __attribute__((ext_vector_type(4)));

// Problem constants: B=2, DIM=128, H=64, W=64, DH=32, HEADS=4, K=7
#define NTOK 8192
#define QSCALE 0.17677669529663687f

__device__ inline float b2f(short s) {
  return __uint_as_float(((unsigned)(unsigned short)s) << 16);
}

// ---------------- K0: convert weights to bf16 ----------------
__global__ __launch_bounds__(256) void k_convw(
    const float* __restrict__ qw, const float* __restrict__ pw,
    const float* __restrict__ w1, const float* __restrict__ w2,
    const float* __restrict__ w3, __hip_bfloat16* __restrict__ dst) {
  int i = blockIdx.x * 256 + threadIdx.x;
  float v;
  if (i < 49152) v = qw[i];
  else if (i < 65536) v = pw[i - 49152];
  else if (i < 81920) v = w1[i - 65536];
  else if (i < 98304) v = w2[i - 81920];
  else if (i < 114688) v = w3[i - 98304];
  else return;
  dst[i] = __float2bfloat16(v);
}

// ---------------- K1: fused NCHW->NHWC + LN1 + QKV GEMM ----------------
// block = 32 tokens; stages x to LDS, LNs, then 32x384 GEMM from LDS A-tile
__global__ __launch_bounds__(256) void k_qkvln(
    const float* __restrict__ x, const float* __restrict__ g,
    const float* __restrict__ be, const float* __restrict__ qkv_b,
    const __hip_bfloat16* __restrict__ wqkv, float* __restrict__ r,
    __hip_bfloat16* __restrict__ qkvb) {
  __shared__ float xt[128][33];
  __shared__ __hip_bfloat16 at[32][136];
  int t = threadIdx.x;
  int m0 = blockIdx.x * 32;
  int b = m0 >> 12;
  int p0 = m0 & 4095;
  const float* xb = x + (size_t)b * 524288;
  int tw = t & 31, th = t >> 5;
#pragma unroll
  for (int i = 0; i < 16; ++i) {
    int c = i * 8 + th;
    xt[c][tw] = xb[c * 4096 + p0 + tw];
  }
  __syncthreads();
  int wid = t >> 6, lane = t & 63;
  float gg0 = g[lane], gg1 = g[lane + 64];
  float bb0 = be[lane], bb1 = be[lane + 64];
#pragma unroll
  for (int it = 0; it < 8; ++it) {
    int tt = wid * 8 + it;
    float v0 = xt[lane][tt], v1 = xt[lane + 64][tt];
    float s = v0 + v1, sq = v0 * v0 + v1 * v1;
#pragma unroll
    for (int off = 32; off; off >>= 1) {
      s += __shfl_xor(s, off);
      sq += __shfl_xor(sq, off);
    }
    float mu = s * (1.f / 128.f);
    float var = sq * (1.f / 128.f) - mu * mu;
    float rs = rsqrtf(var + 1e-5f);
    r[(size_t)(m0 + tt) * 128 + lane] = v0;
    r[(size_t)(m0 + tt) * 128 + 64 + lane] = v1;
    at[tt][lane] = __float2bfloat16((v0 - mu) * rs * gg0 + bb0);
    at[tt][lane + 64] = __float2bfloat16((v1 - mu) * rs * gg1 + bb1);
  }
  __syncthreads();
  // GEMM: 32x384, waves 2(M) x 2(N of 192)
  int mw = wid >> 1, nw = wid & 1;
  int lr = lane & 15, kg = lane >> 4;
  bf16x8 af[4];
#pragma unroll
  for (int ks = 0; ks < 4; ++ks)
    af[ks] = *reinterpret_cast<const bf16x8*>(&at[mw * 16 + lr][ks * 32 + kg * 8]);
  f32x4 acc[12];
#pragma unroll
  for (int nf = 0; nf < 12; ++nf) acc[nf] = f32x4{0, 0, 0, 0};
#pragma unroll
  for (int nf = 0; nf < 12; ++nf) {
    int o = nw * 192 + nf * 16 + lr;
    const __hip_bfloat16* wp = wqkv + o * 128 + kg * 8;
#pragma unroll
    for (int ks = 0; ks < 4; ++ks) {
      bf16x8 bfr = *reinterpret_cast<const bf16x8*>(wp + ks * 32);
      acc[nf] = __builtin_amdgcn_mfma_f32_16x16x32_bf16(af[ks], bfr, acc[nf], 0, 0, 0);
    }
  }
#pragma unroll
  for (int nf = 0; nf < 12; ++nf) {
    int o = nw * 192 + nf * 16 + lr;
    float bv = qkv_b[o];
    float qs = (o < 128) ? QSCALE : 1.f;
#pragma unroll
    for (int rr = 0; rr < 4; ++rr) {
      int m = m0 + mw * 16 + kg * 4 + rr;
      qkvb[(size_t)m * 384 + o] = __float2bfloat16((acc[nf][rr] + bv) * qs);
    }
  }
}

// ---------------- Fused 7x7 neighborhood attention ----------------
__global__ __launch_bounds__(256) void k_attn2(
    const __hip_bfloat16* __restrict__ qkv, const float* __restrict__ rpb,
    __hip_bfloat16* __restrict__ ao) {
  __shared__ float P[4][64];
  int n = blockIdx.x;
  int h = threadIdx.x >> 6, lane = threadIdx.x & 63;
  int b = n >> 12, p = n & 4095, hq = p >> 6, wq = p & 63;
  int hs = min(max(hq - 3, 0), 57), ws0 = min(max(wq - 3, 0), 57);
  int j = lane;
  bool act = j < 49;
  int i7 = j / 7, jc = j - i7 * 7;
  const __hip_bfloat16* qp = qkv + (size_t)n * 384 + h * 32;
  float q[32];
#pragma unroll
  for (int gq = 0; gq < 4; ++gq) {
    bf16x8 v = *reinterpret_cast<const bf16x8*>(qp + gq * 8);
#pragma unroll
    for (int e = 0; e < 8; ++e) q[gq * 8 + e] = b2f(v[e]);
  }
  float sc = -1e30f;
  if (act) {
    int tn = b * 4096 + (hs + i7) * 64 + (ws0 + jc);
    const __hip_bfloat16* kp = qkv + (size_t)tn * 384 + 128 + h * 32;
    float s = 0.f;
#pragma unroll
    for (int gq = 0; gq < 4; ++gq) {
      bf16x8 kv = *reinterpret_cast<const bf16x8*>(kp + gq * 8);
#pragma unroll
      for (int e = 0; e < 8; ++e) s += q[gq * 8 + e] * b2f(kv[e]);
    }
    int bih = hs + i7 - hq + 6, biw = ws0 + jc - wq + 6;
    sc = s + rpb[h * 169 + bih * 13 + biw];
  }
  float mx = sc;
#pragma unroll
  for (int off = 32; off; off >>= 1) mx = fmaxf(mx, __shfl_xor(mx, off));
  float pj = act ? __expf(sc - mx) : 0.f;
  float sum = pj;
#pragma unroll
  for (int off = 32; off; off >>= 1) sum += __shfl_xor(sum, off);
  P[h][j] = pj * (1.f / sum);
  __syncthreads();
  int hi = lane >> 5, d = lane & 31;
  float acc2 = 0.f;
#pragma unroll
  for (int jj = 0; jj < 25; ++jj) {
    int j2 = jj * 2 + hi;
    float pv = P[h][j2];
    int ii = j2 / 7, cc = j2 - ii * 7;
    ii = min(ii, 6);
    int tn = b * 4096 + (hs + ii) * 64 + (ws0 + min(cc, 6));
    float v = b2f(*reinterpret_cast<const short*>(
        qkv + (size_t)tn * 384 + 256 + h * 32 + d));
    acc2 += pv * v;
  }
  acc2 += __shfl_xor(acc2, 32);
  if (hi == 0) ao[(size_t)n * 128 + h * 32 + d] = __float2bfloat16(acc2);
}

// ---------------- helpers for the fused tail ----------------
template <bool A_GLOBAL>
__device__ inline void gemm_stage(const __hip_bfloat16* __restrict__ Aglob,
                                  const __hip_bfloat16 (*abuf)[136],
                                  const __hip_bfloat16* __restrict__ W,
                                  int mw, int nw, int lr, int kg, f32x4 acc[4]) {
  bf16x8 af[4];
  if constexpr (A_GLOBAL) {
#pragma unroll
    for (int ks = 0; ks < 4; ++ks)
      af[ks] = *reinterpret_cast<const bf16x8*>(Aglob + (mw * 16 + lr) * 128 + ks * 32 + kg * 8);
  } else {
#pragma unroll
    for (int ks = 0; ks < 4; ++ks)
      af[ks] = *reinterpret_cast<const bf16x8*>(&abuf[mw * 16 + lr][ks * 32 + kg * 8]);
  }
#pragma unroll
  for (int nf = 0; nf < 4; ++nf) {
    int o = nw * 64 + nf * 16 + lr;
    const __hip_bfloat16* wp = W + o * 128 + kg * 8;
    acc[nf] = f32x4{0, 0, 0, 0};
#pragma unroll
    for (int ks = 0; ks < 4; ++ks) {
      bf16x8 bfr = *reinterpret_cast<const bf16x8*>(wp + ks * 32);
      acc[nf] = __builtin_amdgcn_mfma_f32_16x16x32_bf16(af[ks], bfr, acc[nf], 0, 0, 0);
    }
  }
}

// LN over the 128-col row; writes normalized bf16 into abuf. Ends with the
// red-barrier only; caller must __syncthreads() after (abuf visibility).
__device__ inline void ln_store(f32x4 acc[4], __hip_bfloat16 (*abuf)[136],
                                float2 (*red)[2][16],
                                const float* __restrict__ g,
                                const float* __restrict__ be,
                                int mw, int nw, int lr, int kg) {
  float ps[4] = {0.f, 0.f, 0.f, 0.f}, pq[4] = {0.f, 0.f, 0.f, 0.f};
#pragma unroll
  for (int nf = 0; nf < 4; ++nf)
#pragma unroll
    for (int rr = 0; rr < 4; ++rr) {
      float v = acc[nf][rr];
      ps[rr] += v;
      pq[rr] += v * v;
    }
#pragma unroll
  for (int rr = 0; rr < 4; ++rr)
#pragma unroll
    for (int off = 1; off < 16; off <<= 1) {
      ps[rr] += __shfl_xor(ps[rr], off);
      pq[rr] += __shfl_xor(pq[rr], off);
    }
  if (lr == 0)
#pragma unroll
    for (int rr = 0; rr < 4; ++rr)
      red[mw][nw][kg * 4 + rr] = make_float2(ps[rr], pq[rr]);
  __syncthreads();  // red ready; also: all abuf reads of prev stage complete
  float mu[4], rs[4];
#pragma unroll
  for (int rr = 0; rr < 4; ++rr) {
    float2 a0 = red[mw][0][kg * 4 + rr], a1 = red[mw][1][kg * 4 + rr];
    mu[rr] = (a0.x + a1.x) * (1.f / 128.f);
    float var = (a0.y + a1.y) * (1.f / 128.f) - mu[rr] * mu[rr];
    rs[rr] = rsqrtf(var + 1e-5f);
  }
#pragma unroll
  for (int nf = 0; nf < 4; ++nf) {
    int o = nw * 64 + nf * 16 + lr;
    float gv = g[o], bev = be[o];
#pragma unroll
    for (int rr = 0; rr < 4; ++rr)
      abuf[mw * 16 + kg * 4 + rr][o] =
          __float2bfloat16((acc[nf][rr] - mu[rr]) * rs[rr] * gv + bev);
  }
}

// ---------------- K3: fused tail: proj+LN2 -> w1+res+LN3 -> w2+relu+LN4 -> w3+res -> NCHW ----------------
__global__ __launch_bounds__(256) void k_tail(
    const __hip_bfloat16* __restrict__ ao, const float* __restrict__ r,
    const __hip_bfloat16* __restrict__ wproj, const float* __restrict__ bproj,
    const float* __restrict__ g2, const float* __restrict__ be2,
    const __hip_bfloat16* __restrict__ w1, const float* __restrict__ b1,
    const float* __restrict__ g3, const float* __restrict__ be3,
    const __hip_bfloat16* __restrict__ w2, const float* __restrict__ b2,
    const float* __restrict__ g4, const float* __restrict__ be4,
    const __hip_bfloat16* __restrict__ w3, const float* __restrict__ b3,
    float* __restrict__ out) {
  __shared__ __hip_bfloat16 abuf[32][136];
  __shared__ float2 red[2][2][16];
  int t = threadIdx.x, wid = t >> 6, lane = t & 63;
  int mw = wid >> 1, nw = wid & 1;
  int lr = lane & 15, kg = lane >> 4;
  int m0 = blockIdx.x * 32;
  f32x4 acc[4];
  float x2f[4][4];

  // stage 1: proj + LN2
  gemm_stage<true>(ao + (size_t)m0 * 128, nullptr, wproj, mw, nw, lr, kg, acc);
#pragma unroll
  for (int nf = 0; nf < 4; ++nf) {
    float bv = bproj[nw * 64 + nf * 16 + lr];
#pragma unroll
    for (int rr = 0; rr < 4; ++rr) acc[nf][rr] += bv;
  }
  ln_store(acc, abuf, red, g2, be2, mw, nw, lr, kg);
  __syncthreads();

  // stage 2: w1 + residual r, save x2, LN3
  gemm_stage<false>(nullptr, abuf, w1, mw, nw, lr, kg, acc);
#pragma unroll
  for (int nf = 0; nf < 4; ++nf) {
    int o = nw * 64 + nf * 16 + lr;
    float bv = b1[o];
#pragma unroll
    for (int rr = 0; rr < 4; ++rr) {
      int m = m0 + mw * 16 + kg * 4 + rr;
      float v = acc[nf][rr] + bv + r[(size_t)m * 128 + o];
      x2f[nf][rr] = v;
      acc[nf][rr] = v;
    }
  }
  ln_store(acc, abuf, red, g3, be3, mw, nw, lr, kg);
  __syncthreads();

  // stage 3: w2 + relu + LN4
  gemm_stage<false>(nullptr, abuf, w2, mw, nw, lr, kg, acc);
#pragma unroll
  for (int nf = 0; nf < 4; ++nf) {
    float bv = b2[nw * 64 + nf * 16 + lr];
#pragma unroll
    for (int rr = 0; rr < 4; ++rr) acc[nf][rr] = fmaxf(acc[nf][rr] + bv, 0.f);
  }
  ln_store(acc, abuf, red, g4, be4, mw, nw, lr, kg);
  __syncthreads();

  // stage 4: w3 + x2 residual -> NCHW f32 out
  gemm_stage<false>(nullptr, abuf, w3, mw, nw, lr, kg, acc);
#pragma unroll
  for (int nf = 0; nf < 4; ++nf) {
    int o = nw * 64 + nf * 16 + lr;
    float bv = b3[o];
#pragma unroll
    for (int rr = 0; rr < 4; ++rr) {
      int m = m0 + mw * 16 + kg * 4 + rr;
      float v = acc[nf][rr] + bv + x2f[nf][rr];
      int bb = m >> 12, hw = m & 4095;
      out[(size_t)bb * 524288 + o * 4096 + hw] = v;
    }
  }
}

// ---------------- launch ----------------
extern "C" void kernel_launch(void* const* d_in, const int* in_sizes, int n_in,
                              void* d_out, int out_size, void* d_ws,
                              size_t ws_size, hipStream_t stream) {
  const float* x = (const float*)d_in[0];
  const float* g1 = (const float*)d_in[1];
  const float* be1 = (const float*)d_in[2];
  const float* g2 = (const float*)d_in[3];
  const float* be2 = (const float*)d_in[4];
  const float* g3 = (const float*)d_in[5];
  const float* be3 = (const float*)d_in[6];
  const float* g4 = (const float*)d_in[7];
  const float* be4 = (const float*)d_in[8];
  const float* qkv_w = (const float*)d_in[9];
  const float* qkv_b = (const float*)d_in[10];
  const float* rpb = (const float*)d_in[11];
  const float* proj_w = (const float*)d_in[12];
  const float* proj_b = (const float*)d_in[13];
  const float* w1 = (const float*)d_in[14];
  const float* bl1 = (const float*)d_in[15];
  const float* w2 = (const float*)d_in[16];
  const float* bl2 = (const float*)d_in[17];
  const float* w3 = (const float*)d_in[18];
  const float* bl3 = (const float*)d_in[19];

  char* ws = (char*)d_ws;
  __hip_bfloat16* wb = (__hip_bfloat16*)ws;               // 229KB weights bf16
  __hip_bfloat16* wb_qkv = wb;                            // [384][128]
  __hip_bfloat16* wb_proj = wb + 49152;
  __hip_bfloat16* wb_w1 = wb + 65536;
  __hip_bfloat16* wb_w2 = wb + 81920;
  __hip_bfloat16* wb_w3 = wb + 98304;
  float* r = (float*)(ws + 262144);                       // [8192][128] f32
  __hip_bfloat16* qkvb = (__hip_bfloat16*)(ws + 4456448); // [8192][384] bf16
  __hip_bfloat16* ao = (__hip_bfloat16*)(ws + 10747904);  // [8192][128] bf16

  k_convw<<<448, 256, 0, stream>>>(qkv_w, proj_w, w1, w2, w3, wb);
  k_qkvln<<<256, 256, 0, stream>>>(x, g1, be1, qkv_b, wb_qkv, r, qkvb);
  k_attn2<<<8192, 256, 0, stream>>>(qkvb, rpb, ao);
  k_tail<<<256, 256, 0, stream>>>(ao, r, wb_proj, proj_b, g2, be2, wb_w1, bl1,
                                  g3, be3, wb_w2, bl2, g4, be4, wb_w3, bl3,
                                  (float*)d_out);
}

// Round 7
// 56.123 us; speedup vs baseline: 2.3025x; 1.1315x over previous
//
#include <hip/hip_runtime.h>
#include <hip/hip_bf16.h>
#include <cstdint>

typedef short bf16x8 __attribute__((ext_vector_type(8)));
typedef float f32x4 __attribute__((ext_vector_type(4)));

// Problem constants: B=2, DIM=128, H=64, W=64, DH=32, HEADS=4, K=7
#define NTOK 8192
#define QSCALE 0.17677669529663687f

__device__ inline float b2f(short s) {
  return __uint_as_float(((unsigned)(unsigned short)s) << 16);
}
__device__ inline short f2bs(float x) {
  __hip_bfloat16 b = __float2bfloat16(x);
  return *reinterpret_cast<short*>(&b);
}
__device__ inline bf16x8 ld8(const short* p) {
  short4 lo = *reinterpret_cast<const short4*>(p);
  short4 hi = *reinterpret_cast<const short4*>(p + 4);
  bf16x8 r;
  r[0] = lo.x; r[1] = lo.y; r[2] = lo.z; r[3] = lo.w;
  r[4] = hi.x; r[5] = hi.y; r[6] = hi.z; r[7] = hi.w;
  return r;
}

// ---------------- K0: convert weights to bf16 ----------------
__global__ __launch_bounds__(256) void k_convw(
    const float* __restrict__ qw, const float* __restrict__ pw,
    const float* __restrict__ w1, const float* __restrict__ w2,
    const float* __restrict__ w3, __hip_bfloat16* __restrict__ dst) {
  int i = blockIdx.x * 256 + threadIdx.x;
  float v;
  if (i < 49152) v = qw[i];
  else if (i < 65536) v = pw[i - 49152];
  else if (i < 81920) v = w1[i - 65536];
  else if (i < 98304) v = w2[i - 81920];
  else if (i < 114688) v = w3[i - 98304];
  else return;
  dst[i] = __float2bfloat16(v);
}

// ---------------- K1: fused NCHW->NHWC + LN1 + QKV GEMM ----------------
__global__ __launch_bounds__(256) void k_qkvln(
    const float* __restrict__ x, const float* __restrict__ g,
    const float* __restrict__ be, const float* __restrict__ qkv_b,
    const __hip_bfloat16* __restrict__ wqkv, float* __restrict__ r,
    __hip_bfloat16* __restrict__ qkvb) {
  __shared__ float xt[128][33];
  __shared__ __hip_bfloat16 at[32][136];
  int t = threadIdx.x;
  int m0 = blockIdx.x * 32;
  int b = m0 >> 12;
  int p0 = m0 & 4095;
  const float* xb = x + (size_t)b * 524288;
  int tw = t & 31, th = t >> 5;
#pragma unroll
  for (int i = 0; i < 16; ++i) {
    int c = i * 8 + th;
    xt[c][tw] = xb[c * 4096 + p0 + tw];
  }
  __syncthreads();
  int wid = t >> 6, lane = t & 63;
  float gg0 = g[lane], gg1 = g[lane + 64];
  float bb0 = be[lane], bb1 = be[lane + 64];
#pragma unroll
  for (int it = 0; it < 8; ++it) {
    int tt = wid * 8 + it;
    float v0 = xt[lane][tt], v1 = xt[lane + 64][tt];
    float s = v0 + v1, sq = v0 * v0 + v1 * v1;
#pragma unroll
    for (int off = 32; off; off >>= 1) {
      s += __shfl_xor(s, off);
      sq += __shfl_xor(sq, off);
    }
    float mu = s * (1.f / 128.f);
    float var = sq * (1.f / 128.f) - mu * mu;
    float rs = rsqrtf(var + 1e-5f);
    r[(size_t)(m0 + tt) * 128 + lane] = v0;
    r[(size_t)(m0 + tt) * 128 + 64 + lane] = v1;
    at[tt][lane] = __float2bfloat16((v0 - mu) * rs * gg0 + bb0);
    at[tt][lane + 64] = __float2bfloat16((v1 - mu) * rs * gg1 + bb1);
  }
  __syncthreads();
  int mw = wid >> 1, nw = wid & 1;
  int lr = lane & 15, kg = lane >> 4;
  bf16x8 af[4];
#pragma unroll
  for (int ks = 0; ks < 4; ++ks)
    af[ks] = *reinterpret_cast<const bf16x8*>(&at[mw * 16 + lr][ks * 32 + kg * 8]);
  f32x4 acc[12];
#pragma unroll
  for (int nf = 0; nf < 12; ++nf) acc[nf] = f32x4{0, 0, 0, 0};
#pragma unroll
  for (int nf = 0; nf < 12; ++nf) {
    int o = nw * 192 + nf * 16 + lr;
    const __hip_bfloat16* wp = wqkv + o * 128 + kg * 8;
#pragma unroll
    for (int ks = 0; ks < 4; ++ks) {
      bf16x8 bfr = *reinterpret_cast<const bf16x8*>(wp + ks * 32);
      acc[nf] = __builtin_amdgcn_mfma_f32_16x16x32_bf16(af[ks], bfr, acc[nf], 0, 0, 0);
    }
  }
#pragma unroll
  for (int nf = 0; nf < 12; ++nf) {
    int o = nw * 192 + nf * 16 + lr;
    float bv = qkv_b[o];
    float qs = (o < 128) ? QSCALE : 1.f;
#pragma unroll
    for (int rr = 0; rr < 4; ++rr) {
      int m = m0 + mw * 16 + kg * 4 + rr;
      qkvb[(size_t)m * 384 + o] = __float2bfloat16((acc[nf][rr] + bv) * qs);
    }
  }
}

// ---------------- K2: MFMA neighborhood attention ----------------
// block = 8-token row strip; stage K[98 rows] + V^T in LDS; wave = head.
#define NB 98    // 7*14 staged neighbor tokens
#define KP 132   // K lds pitch (elems): 264B rows, 8B aligned, 2-way banks
#define VP 108   // Vt pitch: 216B
#define PP 132   // P pitch
__global__ __launch_bounds__(256) void k_attn3(
    const __hip_bfloat16* __restrict__ qkv, const float* __restrict__ rpb,
    __hip_bfloat16* __restrict__ ao) {
  __shared__ __align__(16) short smem[104 * KP + 128 * VP + 4 * 8 * PP];
  short* Kl = smem;                   // [104][KP], rows 0..97 staged
  short* Vt = smem + 104 * KP;        // [128][VP] transposed V (d-major)
  short* Pl = Vt + 128 * VP;          // [4][8][PP]
  const short* qs = (const short*)qkv;
  int tid = threadIdx.x;
  int m0 = blockIdx.x * 8;
  int b = m0 >> 12, hq = (m0 >> 6) & 63, c0 = m0 & 63;
  int hs = min(max(hq - 3, 0), 57);
  int cs0 = min(max(c0 - 3, 0), 50);
  // ---- stage K rows + V transposed ----
#pragma unroll
  for (int it = 0; it < 7; ++it) {
    int idx = it * 256 + tid;
    if (idx < NB * 16) {
      int row = idx >> 4, sub = idx & 15;
      int rh = row / 14, rc = row - rh * 14;
      int tr = b * 4096 + (hs + rh) * 64 + min(cs0 + rc, 63);
      const short* src = qs + (size_t)tr * 384 + 128 + sub * 8;
      *(short4*)(Kl + row * KP + sub * 8) = *(const short4*)src;
      *(short4*)(Kl + row * KP + sub * 8 + 4) = *(const short4*)(src + 4);
      const short* sv = qs + (size_t)tr * 384 + 256 + sub * 8;
      short4 vlo = *(const short4*)sv;
      short4 vhi = *(const short4*)(sv + 4);
      int d0 = sub * 8;
      Vt[(d0 + 0) * VP + row] = vlo.x;
      Vt[(d0 + 1) * VP + row] = vlo.y;
      Vt[(d0 + 2) * VP + row] = vlo.z;
      Vt[(d0 + 3) * VP + row] = vlo.w;
      Vt[(d0 + 4) * VP + row] = vhi.x;
      Vt[(d0 + 5) * VP + row] = vhi.y;
      Vt[(d0 + 6) * VP + row] = vhi.z;
      Vt[(d0 + 7) * VP + row] = vhi.w;
    }
  }
  {  // zero Vt cols 98..107 (avoid NaN garbage hitting 0*x in PV)
    int row = tid >> 1, half = tid & 1;
#pragma unroll
    for (int e = 0; e < 5; ++e) Vt[row * VP + NB + half * 5 + e] = 0;
  }
  __syncthreads();
  int h = tid >> 6, lane = tid & 63;
  int lr = lane & 15, kg = lane >> 4;
  // ---- QK^T: 7 MFMAs ----
  int qrow = min(m0 + lr, NTOK - 1);
  bf16x8 aq = *reinterpret_cast<const bf16x8*>(qs + (size_t)qrow * 384 + h * 32 + kg * 8);
  f32x4 sc[7];
#pragma unroll
  for (int nt = 0; nt < 7; ++nt) {
    bf16x8 bk = ld8(Kl + (nt * 16 + lr) * KP + h * 32 + kg * 8);
    sc[nt] = __builtin_amdgcn_mfma_f32_16x16x32_bf16(aq, bk, f32x4{0, 0, 0, 0}, 0, 0, 0);
  }
  // ---- rpb + mask + softmax (row = token on kg, col = neighbor on lr) ----
  int offv[4], cmt[4];
#pragma unroll
  for (int rr = 0; rr < 4; ++rr) {
    int ct = c0 + kg * 4 + rr;
    int ws0 = min(max(ct - 3, 0), 57);
    offv[rr] = ws0 - cs0;
    cmt[rr] = cs0 + 6 - ct;
  }
  float mx[4] = {-3e38f, -3e38f, -3e38f, -3e38f};
#pragma unroll
  for (int nt = 0; nt < 7; ++nt) {
    int nbr = nt * 16 + lr;
    int rh = nbr / 14, rc = nbr - rh * 14;
    bool vn = nbr < NB;
    int ribase = h * 169 + (hs - hq + 6 + rh) * 13 + rc;
#pragma unroll
    for (int rr = 0; rr < 4; ++rr) {
      float v = -1e30f;
      if (vn && (unsigned)(rc - offv[rr]) < 7u) v = sc[nt][rr] + rpb[ribase + cmt[rr]];
      sc[nt][rr] = v;
      mx[rr] = fmaxf(mx[rr], v);
    }
  }
#pragma unroll
  for (int rr = 0; rr < 4; ++rr) {
    mx[rr] = fmaxf(mx[rr], __shfl_xor(mx[rr], 1));
    mx[rr] = fmaxf(mx[rr], __shfl_xor(mx[rr], 2));
    mx[rr] = fmaxf(mx[rr], __shfl_xor(mx[rr], 4));
    mx[rr] = fmaxf(mx[rr], __shfl_xor(mx[rr], 8));
  }
  float sum[4] = {0.f, 0.f, 0.f, 0.f};
#pragma unroll
  for (int nt = 0; nt < 7; ++nt)
#pragma unroll
    for (int rr = 0; rr < 4; ++rr) {
      float e = __expf(sc[nt][rr] - mx[rr]);
      sc[nt][rr] = e;
      sum[rr] += e;
    }
#pragma unroll
  for (int rr = 0; rr < 4; ++rr) {
    sum[rr] += __shfl_xor(sum[rr], 1);
    sum[rr] += __shfl_xor(sum[rr], 2);
    sum[rr] += __shfl_xor(sum[rr], 4);
    sum[rr] += __shfl_xor(sum[rr], 8);
  }
  short* Ph = Pl + h * 8 * PP;
  if (kg < 2) {
#pragma unroll
    for (int rr = 0; rr < 4; ++rr) {
      float inv = 1.f / sum[rr];
      int tok = kg * 4 + rr;
#pragma unroll
      for (int nt = 0; nt < 7; ++nt)
        Ph[tok * PP + nt * 16 + lr] = f2bs(sc[nt][rr] * inv);
      Ph[tok * PP + 112 + lr] = 0;                  // pad cols 112..127
      Ph[tok * PP + 128 + (lr & 3)] = 0;            // pad cols 128..131
    }
  }
  __syncthreads();
  // ---- PV: 8 MFMAs (k = neighbor), B-frags from transposed V ----
  f32x4 o[2] = {f32x4{0, 0, 0, 0}, f32x4{0, 0, 0, 0}};
#pragma unroll
  for (int kt = 0; kt < 4; ++kt) {
    bf16x8 ap = ld8(Ph + (lr & 7) * PP + kt * 32 + kg * 8);
#pragma unroll
    for (int dt = 0; dt < 2; ++dt) {
      bf16x8 bv = ld8(Vt + (h * 32 + dt * 16 + lr) * VP + kt * 32 + kg * 8);
      o[dt] = __builtin_amdgcn_mfma_f32_16x16x32_bf16(ap, bv, o[dt], 0, 0, 0);
    }
  }
  if (kg < 2) {
#pragma unroll
    for (int dt = 0; dt < 2; ++dt)
#pragma unroll
      for (int rr = 0; rr < 4; ++rr) {
        int tok = kg * 4 + rr;
        ao[(size_t)(m0 + tok) * 128 + h * 32 + dt * 16 + lr] =
            __float2bfloat16(o[dt][rr]);
      }
  }
}

// ---------------- helpers for the fused tail ----------------
template <bool A_GLOBAL>
__device__ inline void gemm_stage(const __hip_bfloat16* __restrict__ Aglob,
                                  const __hip_bfloat16 (*abuf)[136],
                                  const __hip_bfloat16* __restrict__ W,
                                  int mw, int nw, int lr, int kg, f32x4 acc[4]) {
  bf16x8 af[4];
  if constexpr (A_GLOBAL) {
#pragma unroll
    for (int ks = 0; ks < 4; ++ks)
      af[ks] = *reinterpret_cast<const bf16x8*>(Aglob + (mw * 16 + lr) * 128 + ks * 32 + kg * 8);
  } else {
#pragma unroll
    for (int ks = 0; ks < 4; ++ks)
      af[ks] = *reinterpret_cast<const bf16x8*>(&abuf[mw * 16 + lr][ks * 32 + kg * 8]);
  }
#pragma unroll
  for (int nf = 0; nf < 4; ++nf) {
    int o = nw * 64 + nf * 16 + lr;
    const __hip_bfloat16* wp = W + o * 128 + kg * 8;
    acc[nf] = f32x4{0, 0, 0, 0};
#pragma unroll
    for (int ks = 0; ks < 4; ++ks) {
      bf16x8 bfr = *reinterpret_cast<const bf16x8*>(wp + ks * 32);
      acc[nf] = __builtin_amdgcn_mfma_f32_16x16x32_bf16(af[ks], bfr, acc[nf], 0, 0, 0);
    }
  }
}

__device__ inline void ln_store(f32x4 acc[4], __hip_bfloat16 (*abuf)[136],
                                float2 (*red)[2][16],
                                const float* __restrict__ g,
                                const float* __restrict__ be,
                                int mw, int nw, int lr, int kg) {
  float ps[4] = {0.f, 0.f, 0.f, 0.f}, pq[4] = {0.f, 0.f, 0.f, 0.f};
#pragma unroll
  for (int nf = 0; nf < 4; ++nf)
#pragma unroll
    for (int rr = 0; rr < 4; ++rr) {
      float v = acc[nf][rr];
      ps[rr] += v;
      pq[rr] += v * v;
    }
#pragma unroll
  for (int rr = 0; rr < 4; ++rr)
#pragma unroll
    for (int off = 1; off < 16; off <<= 1) {
      ps[rr] += __shfl_xor(ps[rr], off);
      pq[rr] += __shfl_xor(pq[rr], off);
    }
  if (lr == 0)
#pragma unroll
    for (int rr = 0; rr < 4; ++rr)
      red[mw][nw][kg * 4 + rr] = make_float2(ps[rr], pq[rr]);
  __syncthreads();
  float mu[4], rs[4];
#pragma unroll
  for (int rr = 0; rr < 4; ++rr) {
    float2 a0 = red[mw][0][kg * 4 + rr], a1 = red[mw][1][kg * 4 + rr];
    mu[rr] = (a0.x + a1.x) * (1.f / 128.f);
    float var = (a0.y + a1.y) * (1.f / 128.f) - mu[rr] * mu[rr];
    rs[rr] = rsqrtf(var + 1e-5f);
  }
#pragma unroll
  for (int nf = 0; nf < 4; ++nf) {
    int o = nw * 64 + nf * 16 + lr;
    float gv = g[o], bev = be[o];
#pragma unroll
    for (int rr = 0; rr < 4; ++rr)
      abuf[mw * 16 + kg * 4 + rr][o] =
          __float2bfloat16((acc[nf][rr] - mu[rr]) * rs[rr] * gv + bev);
  }
}

// ---------------- K3: fused tail ----------------
__global__ __launch_bounds__(256) void k_tail(
    const __hip_bfloat16* __restrict__ ao, const float* __restrict__ r,
    const __hip_bfloat16* __restrict__ wproj, const float* __restrict__ bproj,
    const float* __restrict__ g2, const float* __restrict__ be2,
    const __hip_bfloat16* __restrict__ w1, const float* __restrict__ b1,
    const float* __restrict__ g3, const float* __restrict__ be3,
    const __hip_bfloat16* __restrict__ w2, const float* __restrict__ b2,
    const float* __restrict__ g4, const float* __restrict__ be4,
    const __hip_bfloat16* __restrict__ w3, const float* __restrict__ b3,
    float* __restrict__ out) {
  __shared__ __hip_bfloat16 abuf[32][136];
  __shared__ float2 red[2][2][16];
  int t = threadIdx.x, wid = t >> 6, lane = t & 63;
  int mw = wid >> 1, nw = wid & 1;
  int lr = lane & 15, kg = lane >> 4;
  int m0 = blockIdx.x * 32;
  f32x4 acc[4];
  float x2f[4][4];

  gemm_stage<true>(ao + (size_t)m0 * 128, nullptr, wproj, mw, nw, lr, kg, acc);
#pragma unroll
  for (int nf = 0; nf < 4; ++nf) {
    float bv = bproj[nw * 64 + nf * 16 + lr];
#pragma unroll
    for (int rr = 0; rr < 4; ++rr) acc[nf][rr] += bv;
  }
  ln_store(acc, abuf, red, g2, be2, mw, nw, lr, kg);
  __syncthreads();

  gemm_stage<false>(nullptr, abuf, w1, mw, nw, lr, kg, acc);
#pragma unroll
  for (int nf = 0; nf < 4; ++nf) {
    int o = nw * 64 + nf * 16 + lr;
    float bv = b1[o];
#pragma unroll
    for (int rr = 0; rr < 4; ++rr) {
      int m = m0 + mw * 16 + kg * 4 + rr;
      float v = acc[nf][rr] + bv + r[(size_t)m * 128 + o];
      x2f[nf][rr] = v;
      acc[nf][rr] = v;
    }
  }
  ln_store(acc, abuf, red, g3, be3, mw, nw, lr, kg);
  __syncthreads();

  gemm_stage<false>(nullptr, abuf, w2, mw, nw, lr, kg, acc);
#pragma unroll
  for (int nf = 0; nf < 4; ++nf) {
    float bv = b2[nw * 64 + nf * 16 + lr];
#pragma unroll
    for (int rr = 0; rr < 4; ++rr) acc[nf][rr] = fmaxf(acc[nf][rr] + bv, 0.f);
  }
  ln_store(acc, abuf, red, g4, be4, mw, nw, lr, kg);
  __syncthreads();

  gemm_stage<false>(nullptr, abuf, w3, mw, nw, lr, kg, acc);
#pragma unroll
  for (int nf = 0; nf < 4; ++nf) {
    int o = nw * 64 + nf * 16 + lr;
    float bv = b3[o];
#pragma unroll
    for (int rr = 0; rr < 4; ++rr) {
      int m = m0 + mw * 16 + kg * 4 + rr;
      float v = acc[nf][rr] + bv + x2f[nf][rr];
      int bb = m >> 12, hw = m & 4095;
      out[(size_t)bb * 524288 + o * 4096 + hw] = v;
    }
  }
}

// ---------------- launch ----------------
extern "C" void kernel_launch(void* const* d_in, const int* in_sizes, int n_in,
                              void* d_out, int out_size, void* d_ws,
                              size_t ws_size, hipStream_t stream) {
  const float* x = (const float*)d_in[0];
  const float* g1 = (const float*)d_in[1];
  const float* be1 = (const float*)d_in[2];
  const float* g2 = (const float*)d_in[3];
  const float* be2 = (const float*)d_in[4];
  const float* g3 = (const float*)d_in[5];
  const float* be3 = (const float*)d_in[6];
  const float* g4 = (const float*)d_in[7];
  const float* be4 = (const float*)d_in[8];
  const float* qkv_w = (const float*)d_in[9];
  const float* qkv_b = (const float*)d_in[10];
  const float* rpb = (const float*)d_in[11];
  const float* proj_w = (const float*)d_in[12];
  const float* proj_b = (const float*)d_in[13];
  const float* w1 = (const float*)d_in[14];
  const float* bl1 = (const float*)d_in[15];
  const float* w2 = (const float*)d_in[16];
  const float* bl2 = (const float*)d_in[17];
  const float* w3 = (const float*)d_in[18];
  const float* bl3 = (const float*)d_in[19];

  char* ws = (char*)d_ws;
  __hip_bfloat16* wb = (__hip_bfloat16*)ws;               // weights bf16
  __hip_bfloat16* wb_qkv = wb;                            // [384][128]
  __hip_bfloat16* wb_proj = wb + 49152;
  __hip_bfloat16* wb_w1 = wb + 65536;
  __hip_bfloat16* wb_w2 = wb + 81920;
  __hip_bfloat16* wb_w3 = wb + 98304;
  float* r = (float*)(ws + 262144);                       // [8192][128] f32
  __hip_bfloat16* qkvb = (__hip_bfloat16*)(ws + 4456448); // [8192][384] bf16
  __hip_bfloat16* ao = (__hip_bfloat16*)(ws + 10747904);  // [8192][128] bf16

  k_convw<<<448, 256, 0, stream>>>(qkv_w, proj_w, w1, w2, w3, wb);
  k_qkvln<<<256, 256, 0, stream>>>(x, g1, be1, qkv_b, wb_qkv, r, qkvb);
  k_attn3<<<1024, 256, 0, stream>>>(qkvb, rpb, ao);
  k_tail<<<256, 256, 0, stream>>>(ao, r, wb_proj, proj_b, g2, be2, wb_w1, bl1,
                                  g3, be3, wb_w2, bl2, g4, be4, wb_w3, bl3,
                                  (float*)d_out);
}